// Round 2
// baseline (185.229 us; speedup 1.0000x reference)
//
#include <hip/hip_runtime.h>

namespace {

constexpr int Tt = 32;    // frames (t)
constexpr int Ss = 784;   // h*w = 28*28

// ---------------------------------------------------------------------------
// Kernel 1: per-(b,c) Gram, LDS-free.
//   part[bc][q*32+k] = sum_s x[bc][q][s] * x[bc][k][s]
// 1024 blocks x 256 threads. Each wave owns s4-columns {4j + w}; per column a
// thread loads 4 a-rows (by ty) and 4 b-rows (by tx) as float4 straight from
// global. Per load instr only 8 unique 128B lines (8-way lane broadcast), and
// a/b hit the same lines -> L1-resident. No barriers until the final 4-wave
// LDS reduction. s-unroll x2 => 16 loads in flight.
// ---------------------------------------------------------------------------
__global__ __launch_bounds__(256) void gram_partial(const float* __restrict__ x,
                                                    float* __restrict__ part) {
  const int bc  = blockIdx.x;                       // b*64 + c
  const float* __restrict__ xb = x + (size_t)bc * (Tt * Ss);
  const int tid  = threadIdx.x;
  const int w    = tid >> 6;      // wave 0..3 (owns s4 % 4 == w)
  const int lane = tid & 63;
  const int ty   = lane >> 3;     // q-group 0..7
  const int tx   = lane & 7;      // k-group 0..7

  const float* __restrict__ pa = xb + (size_t)(4 * ty) * Ss;
  const float* __restrict__ pb = xb + (size_t)(4 * tx) * Ss;

  float acc[4][4] = {};

  // s4 = 4*j + w, j = 0..48 (196 float4 columns total). 48 iters unrolled x2 + tail.
  for (int jj = 0; jj < 24; ++jj) {
    const int s0 = 4 * (8 * jj + w);               // float offset of first col
    float4 a0[4], a1[4], b0[4], b1[4];
#pragma unroll
    for (int i = 0; i < 4; ++i) {
      a0[i] = *reinterpret_cast<const float4*>(pa + i * Ss + s0);
      a1[i] = *reinterpret_cast<const float4*>(pa + i * Ss + s0 + 16);
      b0[i] = *reinterpret_cast<const float4*>(pb + i * Ss + s0);
      b1[i] = *reinterpret_cast<const float4*>(pb + i * Ss + s0 + 16);
    }
#pragma unroll
    for (int i = 0; i < 4; ++i)
#pragma unroll
      for (int j = 0; j < 4; ++j) {
        acc[i][j] += a0[i].x * b0[j].x + a0[i].y * b0[j].y +
                     a0[i].z * b0[j].z + a0[i].w * b0[j].w +
                     a1[i].x * b1[j].x + a1[i].y * b1[j].y +
                     a1[i].z * b1[j].z + a1[i].w * b1[j].w;
      }
  }
  {  // tail j = 48: s4 = 192 + w
    const int s0 = 4 * (192 + w);
    float4 a0[4], b0[4];
#pragma unroll
    for (int i = 0; i < 4; ++i) {
      a0[i] = *reinterpret_cast<const float4*>(pa + i * Ss + s0);
      b0[i] = *reinterpret_cast<const float4*>(pb + i * Ss + s0);
    }
#pragma unroll
    for (int i = 0; i < 4; ++i)
#pragma unroll
      for (int j = 0; j < 4; ++j) {
        acc[i][j] += a0[i].x * b0[j].x + a0[i].y * b0[j].y +
                     a0[i].z * b0[j].z + a0[i].w * b0[j].w;
      }
  }

  // reduce the 4 waves' s-partials
  __shared__ float mtmp[4][1024];
#pragma unroll
  for (int i = 0; i < 4; ++i)
#pragma unroll
    for (int j = 0; j < 4; ++j)
      mtmp[w][(4 * ty + i) * 32 + (4 * tx + j)] = acc[i][j];
  __syncthreads();

  float* __restrict__ po = part + (size_t)bc * 1024;
#pragma unroll
  for (int j = 0; j < 4; ++j) {
    const int e = tid + 256 * j;
    po[e] = (mtmp[0][e] + mtmp[1][e]) + (mtmp[2][e] + mtmp[3][e]);
  }
}

// ---------------------------------------------------------------------------
// Kernel 2: reduce partials over c.  msum[b][e] = sum_c part[b*64+c][e]
// ---------------------------------------------------------------------------
__global__ __launch_bounds__(256) void reduce_c(const float* __restrict__ part,
                                                float* __restrict__ msum) {
  const int bid = blockIdx.x;                // 0..63
  const int b   = bid >> 2;
  const int e   = (bid & 3) * 256 + threadIdx.x;   // 0..1023
  const float* __restrict__ p = part + (size_t)b * 64 * 1024 + e;
  float s0 = 0.f, s1 = 0.f, s2 = 0.f, s3 = 0.f;
#pragma unroll
  for (int c = 0; c < 64; c += 4) {
    s0 += p[(size_t)(c + 0) * 1024];
    s1 += p[(size_t)(c + 1) * 1024];
    s2 += p[(size_t)(c + 2) * 1024];
    s3 += p[(size_t)(c + 3) * 1024];
  }
  msum[b * 1024 + e] = (s0 + s1) + (s2 + s3);
}

// ---------------------------------------------------------------------------
// Kernel 3: softmax over the BATCH axis (dim 0) for each (q,k).
// ---------------------------------------------------------------------------
__global__ __launch_bounds__(256) void softmax_b(const float* __restrict__ msum,
                                                 float* __restrict__ msoft) {
  const int e = blockIdx.x * 256 + threadIdx.x;    // 0..1023 (q*32+k)
  float l[16];
  float mx = -3.4e38f;
#pragma unroll
  for (int b = 0; b < 16; ++b) {
    l[b] = msum[b * 1024 + e];
    mx = fmaxf(mx, l[b]);
  }
  float s = 0.f;
#pragma unroll
  for (int b = 0; b < 16; ++b) {
    l[b] = expf(l[b] - mx);
    s += l[b];
  }
  const float inv = 1.f / s;
#pragma unroll
  for (int b = 0; b < 16; ++b) msoft[b * 1024 + e] = l[b] * inv;
}

// ---------------------------------------------------------------------------
// Kernel 4: PV.  out[bc][q][s] = sum_k M[b][q][k] * xv[bc][k][s]
// 2048 blocks (b,c,s-half) x 256 threads. k-loop chunked by 8 with an explicit
// float4 v[8] array -> 8 global loads guaranteed in flight. M in LDS padded
// [32][33] (conflict-free broadcast reads).
// ---------------------------------------------------------------------------
__global__ __launch_bounds__(256) void pv(const float* __restrict__ xv,
                                          const float* __restrict__ msoft,
                                          float* __restrict__ out) {
  const int gbl  = blockIdx.x;                // (b*64+c)*2 + half
  const int bc   = gbl >> 1;
  const int half = gbl & 1;
  const int b    = bc >> 6;
  const float* __restrict__ xvb = xv + (size_t)bc * (Tt * Ss) + half * 392;
  float* __restrict__ ob        = out + (size_t)bc * (Tt * Ss) + half * 392;

  __shared__ float M[32 * 33];
  const int tid = threadIdx.x;
#pragma unroll
  for (int j = 0; j < 4; ++j) {
    const int e = tid + 256 * j;              // q*32 + k
    M[(e >> 5) * 33 + (e & 31)] = msoft[b * 1024 + e];
  }
  __syncthreads();

  const int w    = tid >> 6;
  const int lane = tid & 63;
  const int ty   = lane >> 3;                 // q-group
  const int tx   = lane & 7;                  // s-group
  const int q0   = 4 * ty;
  const float* __restrict__ m0p = &M[(q0 + 0) * 33];
  const float* __restrict__ m1p = &M[(q0 + 1) * 33];
  const float* __restrict__ m2p = &M[(q0 + 2) * 33];
  const float* __restrict__ m3p = &M[(q0 + 3) * 33];

  for (int it = 0; it < 4; ++it) {
    const int s4 = 32 * it + 8 * w + tx;      // local float4 column, 0..97
    if (s4 < 98) {
      const float* __restrict__ src = xvb + 4 * s4;
      float4 a0 = {0.f, 0.f, 0.f, 0.f};
      float4 a1 = {0.f, 0.f, 0.f, 0.f};
      float4 a2 = {0.f, 0.f, 0.f, 0.f};
      float4 a3 = {0.f, 0.f, 0.f, 0.f};
#pragma unroll
      for (int kc = 0; kc < 4; ++kc) {
        float4 v[8];
#pragma unroll
        for (int k8 = 0; k8 < 8; ++k8)
          v[k8] = *reinterpret_cast<const float4*>(src + (size_t)(8 * kc + k8) * Ss);
#pragma unroll
        for (int k8 = 0; k8 < 8; ++k8) {
          const int k = 8 * kc + k8;
          const float m0 = m0p[k], m1 = m1p[k], m2 = m2p[k], m3 = m3p[k];
          a0.x += m0 * v[k8].x; a0.y += m0 * v[k8].y; a0.z += m0 * v[k8].z; a0.w += m0 * v[k8].w;
          a1.x += m1 * v[k8].x; a1.y += m1 * v[k8].y; a1.z += m1 * v[k8].z; a1.w += m1 * v[k8].w;
          a2.x += m2 * v[k8].x; a2.y += m2 * v[k8].y; a2.z += m2 * v[k8].z; a2.w += m2 * v[k8].w;
          a3.x += m3 * v[k8].x; a3.y += m3 * v[k8].y; a3.z += m3 * v[k8].z; a3.w += m3 * v[k8].w;
        }
      }
      *reinterpret_cast<float4*>(ob + (q0 + 0) * Ss + 4 * s4) = a0;
      *reinterpret_cast<float4*>(ob + (q0 + 1) * Ss + 4 * s4) = a1;
      *reinterpret_cast<float4*>(ob + (q0 + 2) * Ss + 4 * s4) = a2;
      *reinterpret_cast<float4*>(ob + (q0 + 3) * Ss + 4 * s4) = a3;
    }
  }
}

}  // namespace

extern "C" void kernel_launch(void* const* d_in, const int* in_sizes, int n_in,
                              void* d_out, int out_size, void* d_ws, size_t ws_size,
                              hipStream_t stream) {
  const float* x  = (const float*)d_in[0];
  const float* xv = (const float*)d_in[1];
  float* out = (float*)d_out;

  // workspace layout (fp32) — identical footprint to round 1 (~4.2 MiB):
  float* part  = (float*)d_ws;            // 1024 x 1024
  float* msum  = part + 1024 * 1024;      // 16 x 1024
  float* msoft = msum + 16 * 1024;        // 16 x 1024

  gram_partial<<<dim3(1024), dim3(256), 0, stream>>>(x, part);
  reduce_c<<<dim3(64), dim3(256), 0, stream>>>(part, msum);
  softmax_b<<<dim3(4), dim3(256), 0, stream>>>(msum, msoft);
  pv<<<dim3(2048), dim3(256), 0, stream>>>(xv, msoft, out);
}

// Round 3
// 104.379 us; speedup vs baseline: 1.7746x; 1.7746x over previous
//
#include <hip/hip_runtime.h>

namespace {

constexpr int Tt = 32;    // frames (t)
constexpr int Ss = 784;   // floats per row (h*w)

// ---------------------------------------------------------------------------
// Kernel 1: per-(b,c) Gram.  part[bc][q*32+k] = sum_s x[bc][q][s]*x[bc][k][s]
// 1024 blocks x 512 threads (8 waves). 4 sequential chunks of 49 float4 cols
// staged in an XOR-swizzled LDS tile [32][56] float4 (28.7 KB), union'd with
// the 8-wave reduce buffer (32 KB) -> 32.75 KB LDS -> 4 blocks/CU (100% occ).
// Compute: thread (w,ty,tx) owns cols c%8==w, acc[4][4] over rows 4ty+i /
// 4tx+j; swizzle col^ty / col^tx makes the 8-way row-broadcast b128 reads
// bank-conflict-free.
// ---------------------------------------------------------------------------
__global__ __launch_bounds__(512) void gram_partial(const float* __restrict__ x,
                                                    float* __restrict__ part) {
  const int bc = blockIdx.x;                       // b*64 + c
  const float* __restrict__ xb = x + (size_t)bc * (Tt * Ss);
  const int tid  = threadIdx.x;
  const int w    = tid >> 6;      // wave 0..7
  const int lane = tid & 63;
  const int ty   = lane >> 3;     // q-group 0..7
  const int tx   = lane & 7;      // k-group 0..7

  __shared__ unsigned char smem[32768];
  float4 (*tile)[56]  = reinterpret_cast<float4(*)[56]>(smem);   // 28672 B
  float  (*mtmp)[1024] = reinterpret_cast<float(*)[1024]>(smem); // 32768 B

  float acc[4][4] = {};

  for (int ch = 0; ch < 4; ++ch) {
    // stage 32 rows x 49 float4 (contiguous 784 B per row)
    for (int f = tid; f < 1568; f += 512) {
      const int row = f / 49;
      const int c   = f - row * 49;
      const float4 v = *reinterpret_cast<const float4*>(xb + row * Ss + ch * 196 + 4 * c);
      tile[row][c ^ ((row >> 2) & 7)] = v;
    }
    __syncthreads();

    for (int c = w; c < 49; c += 8) {
      float4 a4[4], b4[4];
#pragma unroll
      for (int i = 0; i < 4; ++i) a4[i] = tile[4 * ty + i][c ^ ty];
#pragma unroll
      for (int j = 0; j < 4; ++j) b4[j] = tile[4 * tx + j][c ^ tx];
#pragma unroll
      for (int i = 0; i < 4; ++i)
#pragma unroll
        for (int j = 0; j < 4; ++j)
          acc[i][j] += a4[i].x * b4[j].x + a4[i].y * b4[j].y +
                       a4[i].z * b4[j].z + a4[i].w * b4[j].w;
    }
    __syncthreads();   // before restaging (and before mtmp overlay after last chunk)
  }

  // cross-wave reduce (mtmp aliases tile; all tile reads are done)
#pragma unroll
  for (int i = 0; i < 4; ++i)
#pragma unroll
    for (int j = 0; j < 4; ++j)
      mtmp[w][(4 * ty + i) * 32 + 4 * tx + j] = acc[i][j];
  __syncthreads();

  float* __restrict__ po = part + (size_t)bc * 1024;
#pragma unroll
  for (int t = 0; t < 2; ++t) {
    const int e = tid + 512 * t;
    float s = 0.f;
#pragma unroll
    for (int ww = 0; ww < 8; ++ww) s += mtmp[ww][e];
    po[e] = s;
  }
}

// ---------------------------------------------------------------------------
// Kernel 2: reduce partials over c.  msum[b][e] = sum_c part[b*64+c][e]
// ---------------------------------------------------------------------------
__global__ __launch_bounds__(256) void reduce_c(const float* __restrict__ part,
                                                float* __restrict__ msum) {
  const int bid = blockIdx.x;                // 0..63
  const int b   = bid >> 2;
  const int e   = (bid & 3) * 256 + threadIdx.x;   // 0..1023
  const float* __restrict__ p = part + (size_t)b * 64 * 1024 + e;
  float s0 = 0.f, s1 = 0.f, s2 = 0.f, s3 = 0.f;
#pragma unroll
  for (int c = 0; c < 64; c += 4) {
    s0 += p[(size_t)(c + 0) * 1024];
    s1 += p[(size_t)(c + 1) * 1024];
    s2 += p[(size_t)(c + 2) * 1024];
    s3 += p[(size_t)(c + 3) * 1024];
  }
  msum[b * 1024 + e] = (s0 + s1) + (s2 + s3);
}

// ---------------------------------------------------------------------------
// Kernel 3: softmax over the BATCH axis + transpose.
//   mt[b][k*32+q] = softmax_b(msum[b][q*32+k])
// ---------------------------------------------------------------------------
__global__ __launch_bounds__(256) void softmax_b(const float* __restrict__ msum,
                                                 float* __restrict__ mt) {
  const int e = blockIdx.x * 256 + threadIdx.x;    // q*32 + k
  float l[16];
  float mx = -3.4e38f;
#pragma unroll
  for (int b = 0; b < 16; ++b) {
    l[b] = msum[b * 1024 + e];
    mx = fmaxf(mx, l[b]);
  }
  float s = 0.f;
#pragma unroll
  for (int b = 0; b < 16; ++b) {
    l[b] = expf(l[b] - mx);
    s += l[b];
  }
  const float inv = 1.f / s;
  const int et = (e & 31) * 32 + (e >> 5);         // k*32 + q
#pragma unroll
  for (int b = 0; b < 16; ++b) mt[b * 1024 + et] = l[b] * inv;
}

// ---------------------------------------------------------------------------
// Kernel 4: PV.  out[bc][q][s] = sum_k mt[b][k][q] * xv[bc][k][s]
// 4096 blocks = (bc)*4 + s-chunk; 256 threads = 4 waves = 4 q-groups of 8.
// Each wave: lanes 0..48 = one float4 column each -> per-k load is ONE fully
// contiguous 784 B instruction; acc[8] float4 (8 q-rows) in regs; M[k][q]
// broadcast from LDS (wave-uniform addr -> ds_read_b128 pairs). Each block
// reads a distinct 25 KB xv slice -> xv fetched from HBM exactly once.
// ---------------------------------------------------------------------------
__global__ __launch_bounds__(256) void pv(const float* __restrict__ xv,
                                          const float* __restrict__ mt,
                                          float* __restrict__ out) {
  const int gbl   = blockIdx.x;               // bc*4 + chunk
  const int bc    = gbl >> 2;
  const int chunk = gbl & 3;
  const int b     = bc >> 6;
  const float* __restrict__ xvb = xv + (size_t)bc * (Tt * Ss) + chunk * 196;
  float* __restrict__ ob        = out + (size_t)bc * (Tt * Ss) + chunk * 196;

  __shared__ float M[1024];                   // [k][q]
  const int tid = threadIdx.x;
#pragma unroll
  for (int j = 0; j < 4; ++j) M[tid + 256 * j] = mt[b * 1024 + tid + 256 * j];
  __syncthreads();

  const int w    = tid >> 6;                  // q-group 0..3
  const int lane = tid & 63;
  const int q0   = 8 * w;

  if (lane < 49) {
    const float* __restrict__ src = xvb + 4 * lane;
    float4 acc[8] = {};
#pragma unroll 4
    for (int k = 0; k < 32; ++k) {
      const float4 v = *reinterpret_cast<const float4*>(src + (size_t)k * Ss);
      const float* __restrict__ mk = &M[k * 32 + q0];
#pragma unroll
      for (int r = 0; r < 8; ++r) {
        const float m = mk[r];
        acc[r].x += m * v.x; acc[r].y += m * v.y;
        acc[r].z += m * v.z; acc[r].w += m * v.w;
      }
    }
#pragma unroll
    for (int r = 0; r < 8; ++r)
      *reinterpret_cast<float4*>(ob + (size_t)(q0 + r) * Ss + 4 * lane) = acc[r];
  }
}

}  // namespace

extern "C" void kernel_launch(void* const* d_in, const int* in_sizes, int n_in,
                              void* d_out, int out_size, void* d_ws, size_t ws_size,
                              hipStream_t stream) {
  const float* x  = (const float*)d_in[0];
  const float* xv = (const float*)d_in[1];
  float* out = (float*)d_out;

  // workspace (fp32), ~4.2 MiB total — same footprint as round 1:
  float* part = (float*)d_ws;            // 1024 x 1024
  float* msum = part + 1024 * 1024;      // 16 x 1024
  float* mt   = msum + 16 * 1024;        // 16 x 1024 (k-major softmax weights)

  gram_partial<<<dim3(1024), dim3(512), 0, stream>>>(x, part);
  reduce_c<<<dim3(64), dim3(256), 0, stream>>>(part, msum);
  softmax_b<<<dim3(4), dim3(256), 0, stream>>>(msum, mt);
  pv<<<dim3(4096), dim3(256), 0, stream>>>(xv, mt, out);
}